// Round 1
// baseline (468.318 us; speedup 1.0000x reference)
//
#include <hip/hip_runtime.h>
#include <math.h>

#define IN_H 76
#define IN_W 76
#define HW   (IN_H*IN_W)          // 5776
#define BS   32
#define T    20
#define NC   80
#define NCELL (BS*3*HW)           // 554496
#define EPSC 1e-7f

// raw anchors; scaled by stride 608/76 = 8 at use (all /8 values exact in fp32)
__device__ __constant__ float d_anch[18] = {
    12,16, 19,36, 40,28, 36,75, 76,55, 72,146, 142,110, 192,243, 459,401};

__device__ __forceinline__ float sigmoidf_(float x) { return 1.f / (1.f + expf(-x)); }
__device__ __forceinline__ int mask0_of(int l) { return (l == 0) ? 6 : ((l == 1) ? 3 : 0); }

// ---------------- Phase A: per-target anchor match + last-write-wins ----------------
// 1 block, BS*T=640 threads. Zeroes accumulators, builds compact target tables.
__global__ void yolo_phaseA(const float* __restrict__ targets, const int* __restrict__ lp,
                            float* __restrict__ sums, int* __restrict__ n_obj,
                            float4* __restrict__ tbox, int* __restrict__ taux,
                            int* __restrict__ twin) {
    __shared__ int cells[BS * T];
    const int tid = threadIdx.x;           // 0..639
    if (tid < 4) sums[tid] = 0.f;
    if (tid == 4) *n_obj = 0;

    const int l  = *lp;
    const int m0 = mask0_of(l);
    const int b = tid / T, t = tid % T;

    const float* tp = targets + (size_t)(b * T + t) * 5;
    const float gx = tp[0] * (float)IN_W;
    const float gy = tp[1] * (float)IN_H;
    const float gw = tp[2] * (float)IN_W;
    const float gh = tp[3] * (float)IN_H;
    const int  cls = (int)tp[4];

    // argmax over 9 anchors of zero-centered wh IoU (first max wins, like jnp.argmax)
    float best = -1.f; int bn = 0;
    #pragma unroll
    for (int n = 0; n < 9; n++) {
        const float aw = d_anch[2*n]   * 0.125f;
        const float ah = d_anch[2*n+1] * 0.125f;
        const float inter = fminf(gw, aw) * fminf(gh, ah);
        const float uni   = gw * gh + aw * ah - inter;
        const float r = inter / uni;
        if (r > best) { best = r; bn = n; }
    }
    const int k = bn - m0;
    const bool valid = (k >= 0) && (k < 3);
    const int gi = min(max((int)floorf(gx), 0), IN_W - 1);
    const int gj = min(max((int)floorf(gy), 0), IN_H - 1);
    const int cell = valid ? ((k * IN_H + gj) * IN_W + gi) : -1;
    cells[tid] = cell;
    __syncthreads();

    // winner = valid and no LATER valid target in same batch maps to the same cell
    bool win = valid;
    if (valid) {
        for (int t2 = t + 1; t2 < T; t2++)
            if (cells[b * T + t2] == cell) { win = false; break; }
    }

    tbox[tid] = make_float4(gx, gy, gw, gh);
    // pack: valid(1) | k(2) | gj(7) | gi(7) | cls(7)
    taux[tid] = valid ? (1 | (k << 1) | (gj << 3) | (gi << 10) | (cls << 17))
                      : (cls << 17);
    twin[tid] = win ? 1 : 0;
    if (win) atomicAdd(n_obj, 1);
}

// ---------------- Phase B: dense conf-BCE + ignore mask ----------------
// one thread per cell; 554496 = 2166 * 256 exactly (no tail)
__global__ __launch_bounds__(256) void yolo_phaseB(
        const float* __restrict__ inp, const int* __restrict__ lp,
        const float4* __restrict__ tbox, const int* __restrict__ taux,
        float* __restrict__ sums) {
    const int idx = blockIdx.x * 256 + threadIdx.x;
    const int b  = idx / (3 * HW);
    const int r  = idx % (3 * HW);
    const int a  = r / HW;
    const int r2 = r % HW;
    const int j  = r2 / IN_W;
    const int i  = r2 % IN_W;

    const int l  = *lp;
    const int m0 = mask0_of(l);
    const float aw = d_anch[2*(m0+a)]   * 0.125f;
    const float ah = d_anch[2*(m0+a)+1] * 0.125f;

    const float* base = inp + (size_t)(b * 255 + a * 85) * HW + r2;
    const float c0 = base[0];
    const float c1 = base[HW];
    const float c2 = base[2 * HW];
    const float c3 = base[3 * HW];
    const float c4 = base[4 * HW];

    const float px = (float)i + sigmoidf_(c0);
    const float py = (float)j + sigmoidf_(c1);
    const float pw = expf(c2) * aw;
    const float ph = expf(c3) * ah;
    const float conf = sigmoidf_(c4);

    const float pminx = px - pw * 0.5f, pmaxx = px + pw * 0.5f;
    const float pminy = py - ph * 0.5f, pmaxy = py + ph * 0.5f;
    const float pa = pw * ph;

    const float4* tb = tbox + b * T;
    const int*    ta = taux + b * T;
    const int want = 1 | (a << 1) | (j << 3) | (i << 10);

    float best = 0.f;
    bool obj = false;
    #pragma unroll 4
    for (int t = 0; t < T; t++) {
        const float4 g = tb[t];
        const float iw = fmaxf(fminf(g.x + g.z * 0.5f, pmaxx) - fmaxf(g.x - g.z * 0.5f, pminx), 0.f);
        const float ih = fmaxf(fminf(g.y + g.w * 0.5f, pmaxy) - fmaxf(g.y - g.w * 0.5f, pminy), 0.f);
        const float inter = iw * ih;
        const float iou = inter / (g.z * g.w + pa - inter);
        best = fmaxf(best, iou);
        if ((ta[t] & 0x1FFFF) == want) obj = true;
    }

    const float p = fminf(fmaxf(conf, EPSC), 1.f - EPSC);
    const float bce = obj ? -logf(p) : -logf(1.f - p);
    const float mask = (obj || !(best > 0.5f)) ? 1.f : 0.f;

    float v0 = bce * mask, v1 = mask;
    #pragma unroll
    for (int off = 32; off; off >>= 1) {
        v0 += __shfl_down(v0, off, 64);
        v1 += __shfl_down(v1, off, 64);
    }
    if ((threadIdx.x & 63) == 0) {
        atomicAdd(&sums[0], v0);
        atomicAdd(&sums[1], v1);
    }
}

// ---------------- Phase C: CIoU + class-BCE at winner cells ----------------
__global__ void yolo_phaseC(const float* __restrict__ inp, const int* __restrict__ lp,
                            const float4* __restrict__ tbox, const int* __restrict__ taux,
                            const int* __restrict__ twin, float* __restrict__ sums) {
    const int tid = blockIdx.x * 64 + threadIdx.x;
    if (tid >= BS * T) return;
    if (!twin[tid]) return;

    const int b = tid / T;
    const int aux = taux[tid];
    const int k   = (aux >> 1)  & 3;
    const int gj  = (aux >> 3)  & 127;
    const int gi  = (aux >> 10) & 127;
    const int cls = (aux >> 17) & 127;

    const int l  = *lp;
    const int m0 = mask0_of(l);
    const float aw = d_anch[2*(m0+k)]   * 0.125f;
    const float ah = d_anch[2*(m0+k)+1] * 0.125f;

    const float* base = inp + (size_t)(b * 255 + k * 85) * HW + gj * IN_W + gi;
    const float px = (float)gi + sigmoidf_(base[0]);
    const float py = (float)gj + sigmoidf_(base[HW]);
    const float pw = expf(base[2 * HW]) * aw;
    const float ph = expf(base[3 * HW]) * ah;

    const float4 g = tbox[tid];

    // CIoU(b1 = pred, b2 = gt)
    const float p1x = px - pw * 0.5f, p2x = px + pw * 0.5f;
    const float p1y = py - ph * 0.5f, p2y = py + ph * 0.5f;
    const float g1x = g.x - g.z * 0.5f, g2x = g.x + g.z * 0.5f;
    const float g1y = g.y - g.w * 0.5f, g2y = g.y + g.w * 0.5f;
    const float iw = fmaxf(fminf(p2x, g2x) - fmaxf(p1x, g1x), 0.f);
    const float ih = fmaxf(fminf(p2y, g2y) - fmaxf(p1y, g1y), 0.f);
    const float inter = iw * ih;
    const float uni = pw * ph + g.z * g.w - inter;
    const float iou = inter / fmaxf(uni, 1e-6f);
    const float dx = px - g.x, dy = py - g.y;
    const float cd = dx * dx + dy * dy;
    const float ew = fmaxf(fmaxf(p2x, g2x) - fminf(p1x, g1x), 0.f);
    const float eh = fmaxf(fmaxf(p2y, g2y) - fminf(p1y, g1y), 0.f);
    const float ed = ew * ew + eh * eh;
    float ciou = iou - cd / fmaxf(ed, 1e-6f);
    const float dat = atanf(pw / fmaxf(ph, 1e-6f)) - atanf(g.z / fmaxf(g.w, 1e-6f));
    const float v = (4.f / (float)(M_PI * M_PI)) * dat * dat;
    const float alpha = v / fmaxf(1.f - iou + v, 1e-6f);
    ciou = ciou - alpha * v;
    atomicAdd(&sums[2], 1.f - ciou);

    // class BCE (label smoothing = 0)
    float s = 0.f;
    for (int c = 0; c < NC; c++) {
        float pc = sigmoidf_(base[(size_t)(5 + c) * HW]);
        pc = fminf(fmaxf(pc, EPSC), 1.f - EPSC);
        s += (c == cls) ? -logf(pc) : -logf(1.f - pc);
    }
    atomicAdd(&sums[3], s);
}

// ---------------- Phase D: combine ----------------
__global__ void yolo_phaseD(const float* __restrict__ sums, const int* __restrict__ n_obj,
                            const int* __restrict__ lp, float* __restrict__ out) {
    const int l = *lp;
    const float balance = (l == 0) ? 0.4f : ((l == 1) ? 1.0f : 4.0f);
    const float obj_ratio = 5.f * (608.f * 608.f) / (416.f * 416.f);
    const float cls_ratio = (float)NC / 80.f;
    const float no = fmaxf((float)(*n_obj), 1.f);
    const float loss_loc  = sums[2] / no * 0.05f;
    const float loss_cls  = sums[3] / (no * (float)NC) * cls_ratio;
    const float loss_conf = sums[0] / fmaxf(sums[1], 1.f) * balance * obj_ratio;
    out[0] = loss_loc + loss_conf + loss_cls;
}

extern "C" void kernel_launch(void* const* d_in, const int* in_sizes, int n_in,
                              void* d_out, int out_size, void* d_ws, size_t ws_size,
                              hipStream_t stream) {
    const float* inp     = (const float*)d_in[0];
    const float* targets = (const float*)d_in[1];
    const int*   lp      = (const int*)d_in[2];
    float* out = (float*)d_out;

    // workspace layout (≈15.4 KB)
    char* ws = (char*)d_ws;
    float*  sums  = (float*)ws;                    // [0]=conf_bce [1]=mask [2]=loc [3]=cls
    int*    n_obj = (int*)(ws + 16);
    float4* tbox  = (float4*)(ws + 32);            // BS*T float4
    int*    taux  = (int*)(ws + 32 + BS * T * 16); // BS*T
    int*    twin  = taux + BS * T;                 // BS*T

    yolo_phaseA<<<1, BS * T, 0, stream>>>(targets, lp, sums, n_obj, tbox, taux, twin);
    yolo_phaseB<<<NCELL / 256, 256, 0, stream>>>(inp, lp, tbox, taux, sums);
    yolo_phaseC<<<(BS * T) / 64, 64, 0, stream>>>(inp, lp, tbox, taux, twin, sums);
    yolo_phaseD<<<1, 1, 0, stream>>>(sums, n_obj, lp, out);
}

// Round 2
// 238.149 us; speedup vs baseline: 1.9665x; 1.9665x over previous
//
#include <hip/hip_runtime.h>
#include <math.h>

#define IN_H 76
#define IN_W 76
#define HW   (IN_H*IN_W)          // 5776
#define BS   32
#define T    20
#define NC   80
#define NCELL (BS*3*HW)           // 554496
#define EPSC 1e-7f
#define NSLOTA 128                // conf partial slots (each on own 64B line)
#define NSLOTC 8                  // loc/cls partial slots

// raw anchors; scaled by stride 608/76 = 8 at use (all /8 values exact in fp32)
__device__ __constant__ float d_anch[18] = {
    12,16, 19,36, 40,28, 36,75, 76,55, 72,146, 142,110, 192,243, 459,401};

__device__ __forceinline__ float sigmoidf_(float x) { return 1.f / (1.f + expf(-x)); }
__device__ __forceinline__ int mask0_of(int l) { return (l == 0) ? 6 : ((l == 1) ? 3 : 0); }

// ---------------- Phase A: zero partials + per-target anchor match ----------------
// 1 block, BS*T=640 threads.
__global__ void yolo_phaseA(const float* __restrict__ targets, const int* __restrict__ lp,
                            float* __restrict__ partA, float* __restrict__ partC,
                            int* __restrict__ n_obj,
                            float4* __restrict__ tbox, int* __restrict__ taux,
                            int* __restrict__ twin) {
    __shared__ int cells[BS * T];
    const int tid = threadIdx.x;           // 0..639
    for (int z = tid; z < NSLOTA * 16; z += BS * T) partA[z] = 0.f;
    if (tid < NSLOTC * 16) partC[tid] = 0.f;
    if (tid == 0) *n_obj = 0;

    const int l  = *lp;
    const int m0 = mask0_of(l);
    const int b = tid / T, t = tid % T;

    const float* tp = targets + (size_t)(b * T + t) * 5;
    const float gx = tp[0] * (float)IN_W;
    const float gy = tp[1] * (float)IN_H;
    const float gw = tp[2] * (float)IN_W;
    const float gh = tp[3] * (float)IN_H;
    const int  cls = (int)tp[4];

    // argmax over 9 anchors of zero-centered wh IoU (first max wins, like jnp.argmax)
    float best = -1.f; int bn = 0;
    #pragma unroll
    for (int n = 0; n < 9; n++) {
        const float aw = d_anch[2*n]   * 0.125f;
        const float ah = d_anch[2*n+1] * 0.125f;
        const float inter = fminf(gw, aw) * fminf(gh, ah);
        const float uni   = gw * gh + aw * ah - inter;
        const float r = inter / uni;
        if (r > best) { best = r; bn = n; }
    }
    const int k = bn - m0;
    const bool valid = (k >= 0) && (k < 3);
    const int gi = min(max((int)floorf(gx), 0), IN_W - 1);
    const int gj = min(max((int)floorf(gy), 0), IN_H - 1);
    const int cell = valid ? ((k * IN_H + gj) * IN_W + gi) : -1;
    cells[tid] = cell;
    __syncthreads();

    // winner = valid and no LATER valid target in same batch maps to the same cell
    bool win = valid;
    if (valid) {
        for (int t2 = t + 1; t2 < T; t2++)
            if (cells[b * T + t2] == cell) { win = false; break; }
    }

    tbox[tid] = make_float4(gx, gy, gw, gh);
    // pack: valid(1) | k(2) | gj(7) | gi(7) | cls(7)
    taux[tid] = valid ? (1 | (k << 1) | (gj << 3) | (gi << 10) | (cls << 17))
                      : (cls << 17);
    twin[tid] = win ? 1 : 0;
    if (win) atomicAdd(n_obj, 1);
}

// ---------------- Phase B: dense conf-BCE + ignore mask ----------------
// one thread per cell; 554496 = 2166 * 256 exactly (no tail)
__global__ __launch_bounds__(256) void yolo_phaseB(
        const float* __restrict__ inp, const int* __restrict__ lp,
        const float4* __restrict__ tbox, const int* __restrict__ taux,
        float* __restrict__ partA) {
    const int idx = blockIdx.x * 256 + threadIdx.x;
    const int b  = idx / (3 * HW);
    const int r  = idx % (3 * HW);
    const int a  = r / HW;
    const int r2 = r % HW;
    const int j  = r2 / IN_W;
    const int i  = r2 % IN_W;

    const int l  = *lp;
    const int m0 = mask0_of(l);
    const float aw = d_anch[2*(m0+a)]   * 0.125f;
    const float ah = d_anch[2*(m0+a)+1] * 0.125f;

    const float* base = inp + (size_t)(b * 255 + a * 85) * HW + r2;
    const float c0 = base[0];
    const float c1 = base[HW];
    const float c2 = base[2 * HW];
    const float c3 = base[3 * HW];
    const float c4 = base[4 * HW];

    const float px = (float)i + sigmoidf_(c0);
    const float py = (float)j + sigmoidf_(c1);
    const float pw = expf(c2) * aw;
    const float ph = expf(c3) * ah;
    const float conf = sigmoidf_(c4);

    const float pminx = px - pw * 0.5f, pmaxx = px + pw * 0.5f;
    const float pminy = py - ph * 0.5f, pmaxy = py + ph * 0.5f;
    const float pa = pw * ph;

    const float4* tb = tbox + b * T;
    const int*    ta = taux + b * T;
    const int want = 1 | (a << 1) | (j << 3) | (i << 10);

    float best = 0.f;
    bool obj = false;
    #pragma unroll 4
    for (int t = 0; t < T; t++) {
        const float4 g = tb[t];
        const float iw = fmaxf(fminf(g.x + g.z * 0.5f, pmaxx) - fmaxf(g.x - g.z * 0.5f, pminx), 0.f);
        const float ih = fmaxf(fminf(g.y + g.w * 0.5f, pmaxy) - fmaxf(g.y - g.w * 0.5f, pminy), 0.f);
        const float inter = iw * ih;
        const float iou = inter / (g.z * g.w + pa - inter);
        best = fmaxf(best, iou);
        if ((ta[t] & 0x1FFFF) == want) obj = true;
    }

    const float p = fminf(fmaxf(conf, EPSC), 1.f - EPSC);
    const float bce = obj ? -logf(p) : -logf(1.f - p);
    const float mask = (obj || !(best > 0.5f)) ? 1.f : 0.f;

    // wave reduce
    float v0 = bce * mask, v1 = mask;
    #pragma unroll
    for (int off = 32; off; off >>= 1) {
        v0 += __shfl_down(v0, off, 64);
        v1 += __shfl_down(v1, off, 64);
    }
    // block reduce (4 waves) -> one atomic pair per block, spread over 128 lines
    __shared__ float red0[4], red1[4];
    const int lane = threadIdx.x & 63, wid = threadIdx.x >> 6;
    if (lane == 0) { red0[wid] = v0; red1[wid] = v1; }
    __syncthreads();
    if (threadIdx.x == 0) {
        const float s0 = red0[0] + red0[1] + red0[2] + red0[3];
        const float s1 = red1[0] + red1[1] + red1[2] + red1[3];
        const int slot = blockIdx.x & (NSLOTA - 1);
        atomicAdd(&partA[slot * 16 + 0], s0);
        atomicAdd(&partA[slot * 16 + 1], s1);
    }
}

// ---------------- Phase C: CIoU + class-BCE, one WAVE per target ----------------
// 160 blocks x 256 threads = 640 waves
__global__ __launch_bounds__(256) void yolo_phaseC(
        const float* __restrict__ inp, const int* __restrict__ lp,
        const float4* __restrict__ tbox, const int* __restrict__ taux,
        const int* __restrict__ twin, float* __restrict__ partC) {
    const int wid  = blockIdx.x * 4 + (threadIdx.x >> 6);  // target index 0..639
    const int lane = threadIdx.x & 63;
    if (!twin[wid]) return;                                // wave-uniform branch

    const int b = wid / T;
    const int aux = taux[wid];
    const int k   = (aux >> 1)  & 3;
    const int gj  = (aux >> 3)  & 127;
    const int gi  = (aux >> 10) & 127;
    const int cls = (aux >> 17) & 127;

    const int l  = *lp;
    const int m0 = mask0_of(l);

    const float* base = inp + (size_t)(b * 255 + k * 85) * HW + gj * IN_W + gi;

    // class BCE: lane covers class c=lane (+ c=lane+64 for lane<16)
    float s = 0.f;
    {
        float pc = sigmoidf_(base[(size_t)(5 + lane) * HW]);
        pc = fminf(fmaxf(pc, EPSC), 1.f - EPSC);
        s += (lane == cls) ? -logf(pc) : -logf(1.f - pc);
        if (lane < NC - 64) {
            const int c2 = lane + 64;
            float pc2 = sigmoidf_(base[(size_t)(5 + c2) * HW]);
            pc2 = fminf(fmaxf(pc2, EPSC), 1.f - EPSC);
            s += (c2 == cls) ? -logf(pc2) : -logf(1.f - pc2);
        }
    }
    #pragma unroll
    for (int off = 32; off; off >>= 1) s += __shfl_down(s, off, 64);

    if (lane == 0) {
        const float aw = d_anch[2*(m0+k)]   * 0.125f;
        const float ah = d_anch[2*(m0+k)+1] * 0.125f;
        const float px = (float)gi + sigmoidf_(base[0]);
        const float py = (float)gj + sigmoidf_(base[HW]);
        const float pw = expf(base[2 * HW]) * aw;
        const float ph = expf(base[3 * HW]) * ah;

        const float4 g = tbox[wid];
        const float p1x = px - pw * 0.5f, p2x = px + pw * 0.5f;
        const float p1y = py - ph * 0.5f, p2y = py + ph * 0.5f;
        const float g1x = g.x - g.z * 0.5f, g2x = g.x + g.z * 0.5f;
        const float g1y = g.y - g.w * 0.5f, g2y = g.y + g.w * 0.5f;
        const float iw = fmaxf(fminf(p2x, g2x) - fmaxf(p1x, g1x), 0.f);
        const float ih = fmaxf(fminf(p2y, g2y) - fmaxf(p1y, g1y), 0.f);
        const float inter = iw * ih;
        const float uni = pw * ph + g.z * g.w - inter;
        const float iou = inter / fmaxf(uni, 1e-6f);
        const float dx = px - g.x, dy = py - g.y;
        const float cd = dx * dx + dy * dy;
        const float ew = fmaxf(fmaxf(p2x, g2x) - fminf(p1x, g1x), 0.f);
        const float eh = fmaxf(fmaxf(p2y, g2y) - fminf(p1y, g1y), 0.f);
        const float ed = ew * ew + eh * eh;
        float ciou = iou - cd / fmaxf(ed, 1e-6f);
        const float dat = atanf(pw / fmaxf(ph, 1e-6f)) - atanf(g.z / fmaxf(g.w, 1e-6f));
        const float v = (4.f / (float)(M_PI * M_PI)) * dat * dat;
        const float alpha = v / fmaxf(1.f - iou + v, 1e-6f);
        ciou = ciou - alpha * v;

        const int slot = wid & (NSLOTC - 1);
        atomicAdd(&partC[slot * 16 + 0], 1.f - ciou);
        atomicAdd(&partC[slot * 16 + 1], s);
    }
}

// ---------------- Phase D: final reduce + combine (1 wave) ----------------
__global__ void yolo_phaseD(const float* __restrict__ partA, const float* __restrict__ partC,
                            const int* __restrict__ n_obj, const int* __restrict__ lp,
                            float* __restrict__ out) {
    const int lane = threadIdx.x;  // 0..63
    float v0 = partA[lane * 16 + 0] + partA[(lane + 64) * 16 + 0];
    float v1 = partA[lane * 16 + 1] + partA[(lane + 64) * 16 + 1];
    float v2 = (lane < NSLOTC) ? partC[lane * 16 + 0] : 0.f;
    float v3 = (lane < NSLOTC) ? partC[lane * 16 + 1] : 0.f;
    #pragma unroll
    for (int off = 32; off; off >>= 1) {
        v0 += __shfl_down(v0, off, 64);
        v1 += __shfl_down(v1, off, 64);
        v2 += __shfl_down(v2, off, 64);
        v3 += __shfl_down(v3, off, 64);
    }
    if (lane == 0) {
        const int l = *lp;
        const float balance = (l == 0) ? 0.4f : ((l == 1) ? 1.0f : 4.0f);
        const float obj_ratio = 5.f * (608.f * 608.f) / (416.f * 416.f);
        const float cls_ratio = (float)NC / 80.f;
        const float no = fmaxf((float)(*n_obj), 1.f);
        const float loss_loc  = v2 / no * 0.05f;
        const float loss_cls  = v3 / (no * (float)NC) * cls_ratio;
        const float loss_conf = v0 / fmaxf(v1, 1.f) * balance * obj_ratio;
        out[0] = loss_loc + loss_conf + loss_cls;
    }
}

extern "C" void kernel_launch(void* const* d_in, const int* in_sizes, int n_in,
                              void* d_out, int out_size, void* d_ws, size_t ws_size,
                              hipStream_t stream) {
    const float* inp     = (const float*)d_in[0];
    const float* targets = (const float*)d_in[1];
    const int*   lp      = (const int*)d_in[2];
    float* out = (float*)d_out;

    // workspace layout (~24 KB)
    char* ws = (char*)d_ws;
    float*  partA = (float*)ws;                      // 128 slots * 16 floats (conf_bce, mask)
    float*  partC = (float*)(ws + 8192);             // 8 slots * 16 floats (loc, cls)
    int*    n_obj = (int*)(ws + 8704);
    float4* tbox  = (float4*)(ws + 8768);            // 640 float4
    int*    taux  = (int*)(ws + 19008);              // 640
    int*    twin  = (int*)(ws + 21568);              // 640

    yolo_phaseA<<<1, BS * T, 0, stream>>>(targets, lp, partA, partC, n_obj, tbox, taux, twin);
    yolo_phaseB<<<NCELL / 256, 256, 0, stream>>>(inp, lp, tbox, taux, partA);
    yolo_phaseC<<<(BS * T) / 4, 256, 0, stream>>>(inp, lp, tbox, taux, twin, partC);
    yolo_phaseD<<<1, 64, 0, stream>>>(partA, partC, n_obj, lp, out);
}

// Round 3
// 235.198 us; speedup vs baseline: 1.9912x; 1.0125x over previous
//
#include <hip/hip_runtime.h>
#include <math.h>

#define IN_H 76
#define IN_W 76
#define HW   (IN_H*IN_W)          // 5776
#define BS   32
#define T    20
#define NC   80
#define ACT  (3*HW)               // 17328 cells per batch
#define CHUNKS 68                 // ceil(17328/256)
#define NPB  (BS*CHUNKS)          // 2176 partial slots for dense kernel
#define EPSC 1e-7f

// raw anchors; scaled by stride 608/76 = 8 at use (all /8 values exact in fp32)
__device__ __constant__ float d_anch[18] = {
    12,16, 19,36, 40,28, 36,75, 76,55, 72,146, 142,110, 192,243, 459,401};

__device__ __forceinline__ float fsig(float x) {
    return __builtin_amdgcn_rcpf(1.f + __expf(-x));
}
__device__ __forceinline__ int mask0_of(int l) { return (l == 0) ? 6 : ((l == 1) ? 3 : 0); }

// first-occurrence argmax over 9 anchors of zero-centered wh IoU (matches jnp.argmax)
__device__ __forceinline__ int anchor_match(float gw, float gh) {
    float best = -1.f; int bn = 0;
    #pragma unroll
    for (int n = 0; n < 9; n++) {
        const float aw = d_anch[2*n]   * 0.125f;
        const float ah = d_anch[2*n+1] * 0.125f;
        const float inter = fminf(gw, aw) * fminf(gh, ah);
        const float uni   = gw * gh + aw * ah - inter;
        const float r = inter / uni;
        if (r > best) { best = r; bn = n; }
    }
    return bn;
}

// ---------------- dense: conf-BCE + ignore mask; grid (68, 32), batch-uniform blocks ----
__global__ __launch_bounds__(256) void yolo_dense(
        const float* __restrict__ inp, const int* __restrict__ lp,
        const float* __restrict__ targets, float2* __restrict__ partB) {
    __shared__ float4 s_c[T];   // gminx, gminy, gmaxx, gmaxy
    __shared__ float2 s_m[T];   // ga, auxm (int bits)
    const int b = blockIdx.y;
    const int c = blockIdx.x * 256 + threadIdx.x;
    const int l  = *lp;
    const int m0 = mask0_of(l);

    if (threadIdx.x < T) {
        const float* tp = targets + (size_t)(b * T + threadIdx.x) * 5;
        const float gx = tp[0] * 76.f, gy = tp[1] * 76.f;
        const float gw = tp[2] * 76.f, gh = tp[3] * 76.f;
        const int k = anchor_match(gw, gh) - m0;
        const bool valid = (k >= 0) && (k < 3);
        const int gi = min(max((int)floorf(gx), 0), IN_W - 1);
        const int gj = min(max((int)floorf(gy), 0), IN_H - 1);
        const int auxm = valid ? (1 | (k << 1) | (gj << 3) | (gi << 10)) : -1;
        s_c[threadIdx.x] = make_float4(gx - gw * 0.5f, gy - gh * 0.5f,
                                       gx + gw * 0.5f, gy + gh * 0.5f);
        s_m[threadIdx.x] = make_float2(gw * gh, __int_as_float(auxm));
    }
    __syncthreads();

    float v0 = 0.f, v1 = 0.f;
    if (c < ACT) {
        const int a  = c / HW;
        const int r2 = c - a * HW;
        const int j  = r2 / IN_W;
        const int i  = r2 - j * IN_W;
        const float aw = d_anch[2*(m0+a)]   * 0.125f;
        const float ah = d_anch[2*(m0+a)+1] * 0.125f;

        const float* base = inp + ((size_t)b * 255 + a * 85) * HW + r2;
        const float c0 = base[0];
        const float c1 = base[HW];
        const float c2 = base[2 * HW];
        const float c3 = base[3 * HW];
        const float c4 = base[4 * HW];

        const float px = (float)i + fsig(c0);
        const float py = (float)j + fsig(c1);
        const float pw = __expf(c2) * aw;
        const float ph = __expf(c3) * ah;
        const float conf = fsig(c4);

        const float pminx = px - pw * 0.5f, pmaxx = px + pw * 0.5f;
        const float pminy = py - ph * 0.5f, pmaxy = py + ph * 0.5f;
        const float pa = pw * ph;
        const int want = 1 | (a << 1) | (j << 3) | (i << 10);

        bool ign = false, obj = false;
        #pragma unroll
        for (int t = 0; t < T; t++) {
            const float4 gc = s_c[t];
            const float2 gm = s_m[t];
            const float iw = fmaxf(fminf(gc.z, pmaxx) - fmaxf(gc.x, pminx), 0.f);
            const float ih = fmaxf(fminf(gc.w, pmaxy) - fmaxf(gc.y, pminy), 0.f);
            const float inter = iw * ih;
            // iou > 0.5  <=>  inter/(ga+pa-inter) > 0.5  <=>  3*inter > ga+pa  (division-free)
            ign = ign || (3.f * inter > gm.x + pa);
            obj = obj || (__float_as_int(gm.y) == want);
        }
        const float p = fminf(fmaxf(conf, EPSC), 1.f - EPSC);
        const float bce = obj ? -__logf(p) : -__logf(1.f - p);
        const float mask = (obj || !ign) ? 1.f : 0.f;
        v0 = bce * mask; v1 = mask;
    }

    // wave + block reduce -> ONE unconditional store per block (no atomics, no zero-init)
    #pragma unroll
    for (int off = 32; off; off >>= 1) {
        v0 += __shfl_down(v0, off, 64);
        v1 += __shfl_down(v1, off, 64);
    }
    __shared__ float r0[4], r1[4];
    const int lane = threadIdx.x & 63, wv = threadIdx.x >> 6;
    if (lane == 0) { r0[wv] = v0; r1[wv] = v1; }
    __syncthreads();
    if (threadIdx.x == 0) {
        partB[b * CHUNKS + blockIdx.x] =
            make_float2(r0[0] + r0[1] + r0[2] + r0[3],
                        r1[0] + r1[1] + r1[2] + r1[3]);
    }
}

// ---------------- sparse: CIoU + class-BCE, one wave per target; 160 blocks ----------
__global__ __launch_bounds__(256) void yolo_sparse(
        const float* __restrict__ inp, const int* __restrict__ lp,
        const float* __restrict__ targets, float4* __restrict__ partC) {
    const int wid  = blockIdx.x * 4 + (threadIdx.x >> 6);  // target 0..639
    const int lane = threadIdx.x & 63;
    const int b = wid / T, t = wid - b * T;
    const int l  = *lp;
    const int m0 = mask0_of(l);

    // my target (wave-uniform)
    const float* tp = targets + (size_t)(b * T + t) * 5;
    const float gx = tp[0] * 76.f, gy = tp[1] * 76.f;
    const float gw = tp[2] * 76.f, gh = tp[3] * 76.f;
    const int cls = (int)tp[4];
    const int k = anchor_match(gw, gh) - m0;
    const bool valid = (k >= 0) && (k < 3);
    const int gi = min(max((int)floorf(gx), 0), IN_W - 1);
    const int gj = min(max((int)floorf(gy), 0), IN_H - 1);
    const int mycell = valid ? ((k * IN_H + gj) * IN_W + gi) : -1;

    // per-lane cell of target `lane` (for last-write-wins resolution)
    int cell = -3;
    if (lane < T) {
        const float* tq = targets + (size_t)(b * T + lane) * 5;
        const float qx = tq[0] * 76.f, qy = tq[1] * 76.f;
        const float qw = tq[2] * 76.f, qh = tq[3] * 76.f;
        const int qk = anchor_match(qw, qh) - m0;
        if (qk >= 0 && qk < 3) {
            const int qi = min(max((int)floorf(qx), 0), IN_W - 1);
            const int qj = min(max((int)floorf(qy), 0), IN_H - 1);
            cell = (qk * IN_H + qj) * IN_W + qi;
        } else cell = -1;
    }
    const unsigned long long later = __ballot((lane > t) && (cell == mycell));
    const bool win = valid && (later == 0ULL);   // wave-uniform
    if (!win) {
        if (lane == 0) partC[wid] = make_float4(0.f, 0.f, 0.f, 0.f);
        return;
    }

    const float* base = inp + ((size_t)b * 255 + k * 85) * HW + gj * IN_W + gi;

    // class BCE: lane covers class lane (+ lane+64 for lane<16)
    float s;
    {
        float pc = fminf(fmaxf(fsig(base[(size_t)(5 + lane) * HW]), EPSC), 1.f - EPSC);
        s = (lane == cls) ? -__logf(pc) : -__logf(1.f - pc);
        if (lane < NC - 64) {
            const int c2 = lane + 64;
            float pc2 = fminf(fmaxf(fsig(base[(size_t)(5 + c2) * HW]), EPSC), 1.f - EPSC);
            s += (c2 == cls) ? -__logf(pc2) : -__logf(1.f - pc2);
        }
    }
    #pragma unroll
    for (int off = 32; off; off >>= 1) s += __shfl_down(s, off, 64);

    if (lane == 0) {
        const float aw = d_anch[2*(m0+k)]   * 0.125f;
        const float ah = d_anch[2*(m0+k)+1] * 0.125f;
        const float px = (float)gi + fsig(base[0]);
        const float py = (float)gj + fsig(base[HW]);
        const float pw = __expf(base[2 * HW]) * aw;
        const float ph = __expf(base[3 * HW]) * ah;

        const float p1x = px - pw * 0.5f, p2x = px + pw * 0.5f;
        const float p1y = py - ph * 0.5f, p2y = py + ph * 0.5f;
        const float g1x = gx - gw * 0.5f, g2x = gx + gw * 0.5f;
        const float g1y = gy - gh * 0.5f, g2y = gy + gh * 0.5f;
        const float iw = fmaxf(fminf(p2x, g2x) - fmaxf(p1x, g1x), 0.f);
        const float ih = fmaxf(fminf(p2y, g2y) - fmaxf(p1y, g1y), 0.f);
        const float inter = iw * ih;
        const float uni = pw * ph + gw * gh - inter;
        const float iou = inter / fmaxf(uni, 1e-6f);
        const float dx = px - gx, dy = py - gy;
        const float cd = dx * dx + dy * dy;
        const float ew = fmaxf(fmaxf(p2x, g2x) - fminf(p1x, g1x), 0.f);
        const float eh = fmaxf(fmaxf(p2y, g2y) - fminf(p1y, g1y), 0.f);
        const float ed = ew * ew + eh * eh;
        float ciou = iou - cd / fmaxf(ed, 1e-6f);
        const float dat = atanf(pw / fmaxf(ph, 1e-6f)) - atanf(gw / fmaxf(gh, 1e-6f));
        const float v = (4.f / (float)(M_PI * M_PI)) * dat * dat;
        const float alpha = v / fmaxf(1.f - iou + v, 1e-6f);
        ciou = ciou - alpha * v;
        partC[wid] = make_float4(1.f - ciou, s, 1.f, 0.f);
    }
}

// ---------------- final: reduce 2176 float2 + 640 float4, combine ----------------
__global__ __launch_bounds__(256) void yolo_final(
        const float2* __restrict__ partB, const float4* __restrict__ partC,
        const int* __restrict__ lp, float* __restrict__ out) {
    float a0 = 0.f, a1 = 0.f, a2 = 0.f, a3 = 0.f, a4 = 0.f;
    for (int k = threadIdx.x; k < NPB; k += 256) {
        const float2 v = partB[k]; a0 += v.x; a1 += v.y;
    }
    for (int k = threadIdx.x; k < BS * T; k += 256) {
        const float4 v = partC[k]; a2 += v.x; a3 += v.y; a4 += v.z;
    }
    #pragma unroll
    for (int off = 32; off; off >>= 1) {
        a0 += __shfl_down(a0, off, 64);
        a1 += __shfl_down(a1, off, 64);
        a2 += __shfl_down(a2, off, 64);
        a3 += __shfl_down(a3, off, 64);
        a4 += __shfl_down(a4, off, 64);
    }
    __shared__ float red[4][5];
    const int lane = threadIdx.x & 63, wv = threadIdx.x >> 6;
    if (lane == 0) { red[wv][0]=a0; red[wv][1]=a1; red[wv][2]=a2; red[wv][3]=a3; red[wv][4]=a4; }
    __syncthreads();
    if (threadIdx.x == 0) {
        float s0=0,s1=0,s2=0,s3=0,s4=0;
        #pragma unroll
        for (int w = 0; w < 4; w++) {
            s0+=red[w][0]; s1+=red[w][1]; s2+=red[w][2]; s3+=red[w][3]; s4+=red[w][4];
        }
        const int l = *lp;
        const float balance = (l == 0) ? 0.4f : ((l == 1) ? 1.0f : 4.0f);
        const float obj_ratio = 5.f * (608.f * 608.f) / (416.f * 416.f);
        const float no = fmaxf(s4, 1.f);
        const float loss_loc  = s2 / no * 0.05f;
        const float loss_cls  = s3 / (no * (float)NC);   // cls_ratio = 1
        const float loss_conf = s0 / fmaxf(s1, 1.f) * balance * obj_ratio;
        out[0] = loss_loc + loss_conf + loss_cls;
    }
}

extern "C" void kernel_launch(void* const* d_in, const int* in_sizes, int n_in,
                              void* d_out, int out_size, void* d_ws, size_t ws_size,
                              hipStream_t stream) {
    const float* inp     = (const float*)d_in[0];
    const float* targets = (const float*)d_in[1];
    const int*   lp      = (const int*)d_in[2];
    float* out = (float*)d_out;

    // workspace: every slot written unconditionally each call -> poison-safe, no memset
    char* ws = (char*)d_ws;
    float2* partB = (float2*)ws;                 // 2176 * 8 B
    float4* partC = (float4*)(ws + NPB * 8);     // 640 * 16 B (offset 17408, 16B-aligned)

    dim3 gridB(CHUNKS, BS);
    yolo_dense <<<gridB, 256, 0, stream>>>(inp, lp, targets, partB);
    yolo_sparse<<<(BS * T) / 4, 256, 0, stream>>>(inp, lp, targets, partC);
    yolo_final <<<1, 256, 0, stream>>>(partB, partC, lp, out);
}